// Round 3
// baseline (3793.033 us; speedup 1.0000x reference)
//
#include <hip/hip_runtime.h>
#include <math.h>

#define DEPTH 3
#define HEADS 8
#define DIM 512
#define NCLS 4
#define EPSV 1e-5f
#define BB 2
#define NN 2560
#define HD 64
#define ATT_SCALE 0.125f
#define QB 8

typedef __attribute__((ext_vector_type(8))) short bf16x8;
typedef __attribute__((ext_vector_type(4))) float f32x4;

// ---------------- bf16 split helpers (hi + lo ~= fp32, RNE both) ----------------
__device__ inline unsigned short bf16_rne(float f) {
    unsigned int u = __float_as_uint(f);
    u += 0x7FFFu + ((u >> 16) & 1u);
    return (unsigned short)(u >> 16);
}
__device__ inline float bf16_tof(unsigned short h) {
    return __uint_as_float(((unsigned int)h) << 16);
}
__device__ inline void split2(float f, unsigned short& hi, unsigned short& lo) {
    hi = bf16_rne(f);
    lo = bf16_rne(f - bf16_tof(hi));
}

__device__ inline float gelu_tanh(float x) {
    float x3 = x * x * x;
    return 0.5f * x * (1.f + tanhf(0.7978845608028654f * (x + 0.044715f * x3)));
}

// LDS chunk swizzle: plane rows are 64B = 4 x 16B chunks. chunk' = chunk ^ ((row>>1)&3).
__device__ inline int swz(int row, int chunk) { return chunk ^ ((row >> 1) & 3); }

// async global->LDS, 16B per lane, wave-uniform LDS base + lane*16
__device__ inline void gll16(const void* g, void* l) {
    __builtin_amdgcn_global_load_lds(
        (const __attribute__((address_space(1))) void*)g,
        (__attribute__((address_space(3))) void*)l,
        16, 0, 0);
}

// Stage a bf16 plane tile [ROWS][32] into LDS (linear dest, source-swizzled).
template<int ROWS>
__device__ inline void stage_plane(const unsigned short* gp, int ldp,
                                   unsigned short* ls, int lane, int wave) {
#pragma unroll
    for (int q = 0; q < ROWS / 64; ++q) {
        int base = wave * (ROWS * 16) + q * 1024;   // wave-uniform byte base
        int lpos = base + lane * 16;
        int row  = lpos >> 6;
        int cl   = (lpos >> 4) & 3;
        int cg   = swz(row, cl);
        gll16(gp + (size_t)row * ldp + cg * 8, (char*)ls + base);
    }
}

// ---------------- MFMA split-bf16 GEMM ----------------
// C[BMxBN tile] = alpha * A[M,K] @ B^T[N,K] (+bias)(gelu)(+=resid/atomic)
// SPLITK>1: grid.z = SPLITK (nh must be 1), partials atomicAdd'ed into fp32 Cf.
template<int BN, bool DO_GELU, bool DO_RESID, bool SPLIT_OUT, bool ZSWZ, int SPLITK>
__global__ __launch_bounds__(256, (BN == 128 ? 2 : 3)) void gemm_mfma(
    const unsigned short* __restrict__ A_hi, const unsigned short* __restrict__ A_lo,
    int lda, long long sAb, long long sAh,
    const unsigned short* __restrict__ B_hi, const unsigned short* __restrict__ B_lo,
    int ldb, long long sBb, long long sBh,
    float* __restrict__ Cf,
    unsigned short* __restrict__ C_hi, unsigned short* __restrict__ C_lo,
    int ldc, long long sCb, long long sCh,
    int K, float alpha, const float* __restrict__ bias, int nh)
{
    constexpr int BM = 128;
    constexpr int WAVES_N = (BN == 128) ? 2 : 1;
    constexpr int WM = (WAVES_N == 2) ? 64 : 32;
    constexpr int WN = 64;
    constexpr int MF = WM / 16;
    constexpr int NF = WN / 16;

    __shared__ unsigned short As_hi[BM * 32], As_lo[BM * 32];
    __shared__ unsigned short Bs_hi[BN * 32], Bs_lo[BN * 32];

    int bx = blockIdx.x, by = blockIdx.y, bzz = blockIdx.z;
    if constexpr (ZSWZ) {
        int gx = gridDim.x, gy = gridDim.y, gz = gridDim.z;
        int pb = gx * gy;
        int total = pb * gz;
        int flat = bx + gx * (by + gy * bzz);
        int cpx = total >> 3;
        int nf = (flat & 7) * cpx + (flat >> 3);
        bzz = nf / pb;
        int r = nf - bzz * pb;
        by = r / gx;
        bx = r - by * gx;
    }

    int kz = 0;
    if constexpr (SPLITK > 1) { kz = bzz; bzz = 0; }

    const int bz = bzz / nh, hz = bzz % nh;
    const long long aoff = (long long)bz * sAb + (long long)hz * sAh;
    const long long boff = (long long)bz * sBb + (long long)hz * sBh;
    const long long coff = (long long)bz * sCb + (long long)hz * sCh;
    A_hi += aoff; A_lo += aoff;
    B_hi += boff; B_lo += boff;
    if (SPLIT_OUT) { C_hi += coff; C_lo += coff; } else { Cf += coff; }

    const int tid  = threadIdx.x;
    const int lane = tid & 63;
    const int wave = tid >> 6;
    const int row0 = by * BM;
    const int n0   = bx * BN;
    const int wr = (WAVES_N == 2) ? (wave >> 1) : wave;
    const int wc = (WAVES_N == 2) ? (wave & 1) : 0;
    const int lr = lane & 15;
    const int cg = lane >> 4;

    f32x4 acc[MF][NF];
#pragma unroll
    for (int m = 0; m < MF; ++m)
#pragma unroll
        for (int n = 0; n < NF; ++n)
#pragma unroll
            for (int i = 0; i < 4; ++i) acc[m][n][i] = 0.f;

    const int kb = kz * (K / SPLITK);
    const int ke = kb + K / SPLITK;
    for (int k0 = kb; k0 < ke; k0 += 32) {
        stage_plane<BM>(A_hi + (size_t)row0 * lda + k0, lda, As_hi, lane, wave);
        stage_plane<BM>(A_lo + (size_t)row0 * lda + k0, lda, As_lo, lane, wave);
        stage_plane<BN>(B_hi + (size_t)n0 * ldb + k0, ldb, Bs_hi, lane, wave);
        stage_plane<BN>(B_lo + (size_t)n0 * ldb + k0, ldb, Bs_lo, lane, wave);
        __syncthreads();

        bf16x8 ah[MF], al[MF], bh[NF], bl[NF];
#pragma unroll
        for (int m = 0; m < MF; ++m) {
            int r = wr * WM + m * 16 + lr;
            int idx = r * 32 + swz(r, cg) * 8;
            ah[m] = *(const bf16x8*)&As_hi[idx];
            al[m] = *(const bf16x8*)&As_lo[idx];
        }
#pragma unroll
        for (int n = 0; n < NF; ++n) {
            int r = wc * WN + n * 16 + lr;
            int idx = r * 32 + swz(r, cg) * 8;
            bh[n] = *(const bf16x8*)&Bs_hi[idx];
            bl[n] = *(const bf16x8*)&Bs_lo[idx];
        }
#pragma unroll
        for (int m = 0; m < MF; ++m)
#pragma unroll
            for (int n = 0; n < NF; ++n) {
                acc[m][n] = __builtin_amdgcn_mfma_f32_16x16x32_bf16(ah[m], bh[n], acc[m][n], 0, 0, 0);
                acc[m][n] = __builtin_amdgcn_mfma_f32_16x16x32_bf16(ah[m], bl[n], acc[m][n], 0, 0, 0);
                acc[m][n] = __builtin_amdgcn_mfma_f32_16x16x32_bf16(al[m], bh[n], acc[m][n], 0, 0, 0);
            }
        __syncthreads();
    }

    // epilogue: D lane map col = lane&15, row = (lane>>4)*4 + i
    float bv[NF];
#pragma unroll
    for (int n = 0; n < NF; ++n) {
        int col = n0 + wc * WN + n * 16 + lr;
        bv[n] = (bias && kz == 0) ? bias[col] : 0.f;
    }
#pragma unroll
    for (int m = 0; m < MF; ++m) {
#pragma unroll
        for (int n = 0; n < NF; ++n) {
            int col = n0 + wc * WN + n * 16 + lr;
#pragma unroll
            for (int i = 0; i < 4; ++i) {
                int row = row0 + wr * WM + m * 16 + cg * 4 + i;
                size_t off = (size_t)row * ldc + col;
                float r = alpha * acc[m][n][i] + bv[n];
                if constexpr (DO_GELU) r = gelu_tanh(r);
                if constexpr (SPLITK > 1) {
                    atomicAdd(&Cf[off], r);
                } else if constexpr (SPLIT_OUT) {
                    unsigned short h, l;
                    split2(r, h, l);
                    C_hi[off] = h; C_lo[off] = l;
                } else {
                    if constexpr (DO_RESID) r += Cf[off];
                    Cf[off] = r;
                }
            }
        }
    }
}

// ---------------- LayerNorm -> hi/lo bf16 planes ----------------
__global__ __launch_bounds__(256) void ln_split_kernel(const float* __restrict__ x,
                                                       const float* __restrict__ g,
                                                       const float* __restrict__ b,
                                                       unsigned short* __restrict__ ohi,
                                                       unsigned short* __restrict__ olo) {
    int wave = threadIdx.x >> 6;
    int lane = threadIdx.x & 63;
    int row  = blockIdx.x * 4 + wave;
    const float* xr = x + (size_t)row * DIM;
    float v[8];
    float s = 0.f, ss = 0.f;
#pragma unroll
    for (int i = 0; i < 8; ++i) {
        v[i] = xr[lane + i * 64];
        s += v[i]; ss += v[i] * v[i];
    }
#pragma unroll
    for (int off = 32; off >= 1; off >>= 1) {
        s  += __shfl_xor(s,  off, 64);
        ss += __shfl_xor(ss, off, 64);
    }
    float mu   = s * (1.f / DIM);
    float var  = ss * (1.f / DIM) - mu * mu;
    float rstd = rsqrtf(var + EPSV);
    size_t base = (size_t)row * DIM;
#pragma unroll
    for (int i = 0; i < 8; ++i) {
        int c = lane + i * 64;
        float r = (v[i] - mu) * rstd * g[c] + b[c];
        unsigned short h, l;
        split2(r, h, l);
        ohi[base + c] = h; olo[base + c] = l;
    }
}

// ---------------- transpose + split: fp32 [R][C] -> hi/lo bf16 [C][R] ----------------
__global__ __launch_bounds__(256) void tsplit_kernel(
    const float* __restrict__ in, int ldin, long long inBS,
    unsigned short* __restrict__ ohi, unsigned short* __restrict__ olo,
    int ldout, long long outBS) {
    __shared__ float tile[32][33];
    const float* src = in + (size_t)blockIdx.z * inBS;
    int r0 = blockIdx.y * 32, c0 = blockIdx.x * 32;
    int t = threadIdx.x;
    int r = t >> 3, cq = (t & 7) * 4;
    float4 v = *(const float4*)&src[(size_t)(r0 + r) * ldin + c0 + cq];
    tile[r][cq] = v.x; tile[r][cq + 1] = v.y; tile[r][cq + 2] = v.z; tile[r][cq + 3] = v.w;
    __syncthreads();
    unsigned short h[4], l[4];
#pragma unroll
    for (int i = 0; i < 4; ++i) split2(tile[cq + i][r], h[i], l[i]);
    size_t off = (size_t)blockIdx.z * outBS + (size_t)(c0 + r) * ldout + r0 + cq;
    *(ushort4*)&ohi[off] = make_ushort4(h[0], h[1], h[2], h[3]);
    *(ushort4*)&olo[off] = make_ushort4(l[0], l[1], l[2], l[3]);
}

// ---------------- Fused masked softmax + PV ----------------
// grid (NN/QB, HEADS, BB), 256 threads. Per block: QB q-rows of one (b,h).
// Phase 1: register softmax, write normalized fp32 probs to d_out, deposit bf16
//          probs (swizzled) in LDS. Phase 2: PV via MFMA, V^T planes from L2.
__global__ __launch_bounds__(256) void softmax_pv_kernel(
    float* __restrict__ attn, const int* __restrict__ mask,
    const unsigned short* __restrict__ vt_hi, const unsigned short* __restrict__ vt_lo,
    unsigned short* __restrict__ o_hi, unsigned short* __restrict__ o_lo)
{
    __shared__ unsigned short P[QB * NN];       // 41 KB, chunk-swizzled bf16 probs
    __shared__ float Ored[4][QB * 64];          // 8 KB per-wave partials

    const int qb = blockIdx.x, h = blockIdx.y, b = blockIdx.z;
    const int q0 = qb * QB;
    const int tid = threadIdx.x, lane = tid & 63, wave = tid >> 6;
    float* base = attn + (((size_t)(b * HEADS + h)) * NN + q0) * NN;

    bool mok[NCLS];
#pragma unroll
    for (int c = 0; c < NCLS; ++c) mok[c] = (mask[b * NCLS + c] != 0);

    // ---- phase 1: softmax, 2 rows per wave ----
    for (int rr = 0; rr < 2; ++rr) {
        int row = wave * 2 + rr;
        float* rp = base + (size_t)row * NN;
        float4 v[10];
        bool okv[10];
        float lmax = -INFINITY;
#pragma unroll
        for (int i = 0; i < 10; ++i) {
            int k4 = lane + 64 * i;                 // float4 index; cols 4k4..4k4+3
            v[i] = *(const float4*)&rp[4 * k4];
            int cls = k4 >> 7;                      // (4*k4)>>9
            okv[i] = (cls >= NCLS) || mok[cls];
            if (okv[i]) lmax = fmaxf(lmax,
                fmaxf(fmaxf(v[i].x, v[i].y), fmaxf(v[i].z, v[i].w)));
        }
#pragma unroll
        for (int off = 32; off >= 1; off >>= 1) lmax = fmaxf(lmax, __shfl_xor(lmax, off, 64));
        float lsum = 0.f;
#pragma unroll
        for (int i = 0; i < 10; ++i) {
            if (okv[i]) {
                v[i].x = __expf(v[i].x - lmax); v[i].y = __expf(v[i].y - lmax);
                v[i].z = __expf(v[i].z - lmax); v[i].w = __expf(v[i].w - lmax);
                lsum += v[i].x + v[i].y + v[i].z + v[i].w;
            } else {
                v[i] = make_float4(0.f, 0.f, 0.f, 0.f);
            }
        }
#pragma unroll
        for (int off = 32; off >= 1; off >>= 1) lsum += __shfl_xor(lsum, off, 64);
        float inv = 1.f / lsum;
#pragma unroll
        for (int i = 0; i < 10; ++i) {
            int k4 = lane + 64 * i;
            float4 p = make_float4(v[i].x * inv, v[i].y * inv, v[i].z * inv, v[i].w * inv);
            *(float4*)&rp[4 * k4] = p;
            // deposit bf16 into LDS, chunk-swizzled: c = k4>>1, c' = c ^ (row&7)
            int c = k4 >> 1, sub = k4 & 1;
            int cp = c ^ (row & 7);
            ushort4 pk = make_ushort4(bf16_rne(p.x), bf16_rne(p.y), bf16_rne(p.z), bf16_rne(p.w));
            *(ushort4*)&P[row * NN + cp * 8 + sub * 4] = pk;
        }
    }
    __syncthreads();

    // ---- phase 2: PV, K split across 4 waves ----
    const int lr = lane & 15;
    const int cg = lane >> 4;
    const unsigned short* vbh = vt_hi + (size_t)b * DIM * NN + (size_t)(h * HD) * NN;
    const unsigned short* vbl = vt_lo + (size_t)b * DIM * NN + (size_t)(h * HD) * NN;

    f32x4 acc[4];
#pragma unroll
    for (int n = 0; n < 4; ++n)
#pragma unroll
        for (int i = 0; i < 4; ++i) acc[n][i] = 0.f;

    const bf16x8 az = {0, 0, 0, 0, 0, 0, 0, 0};
#pragma unroll 2
    for (int t = 0; t < NN / (4 * 32); ++t) {
        int k0 = wave * (NN / 4) + t * 32;
        bf16x8 ah = az;
        if (lr < QB) ah = *(const bf16x8*)&P[lr * NN + (((k0 >> 3) + cg) ^ lr) * 8];
        bf16x8 bh[4], bl[4];
#pragma unroll
        for (int n = 0; n < 4; ++n) {
            size_t doff = (size_t)(n * 16 + lr) * NN + k0 + cg * 8;
            bh[n] = *(const bf16x8*)&vbh[doff];
            bl[n] = *(const bf16x8*)&vbl[doff];
        }
#pragma unroll
        for (int n = 0; n < 4; ++n) {
            acc[n] = __builtin_amdgcn_mfma_f32_16x16x32_bf16(ah, bh[n], acc[n], 0, 0, 0);
            acc[n] = __builtin_amdgcn_mfma_f32_16x16x32_bf16(ah, bl[n], acc[n], 0, 0, 0);
        }
    }

    // valid output rows: r = cg*4 + i for cg<2 (rows 0..7)
    if (cg < 2) {
#pragma unroll
        for (int n = 0; n < 4; ++n)
#pragma unroll
            for (int i = 0; i < 4; ++i)
                Ored[wave][(cg * 4 + i) * 64 + n * 16 + lr] = acc[n][i];
    }
    __syncthreads();

#pragma unroll
    for (int e = tid; e < QB * 64; e += 256) {
        float s = Ored[0][e] + Ored[1][e] + Ored[2][e] + Ored[3][e];
        int r = e >> 6, c = e & 63;
        unsigned short hh, ll;
        split2(s, hh, ll);
        size_t off = (size_t)(b * NN + q0 + r) * DIM + h * HD + c;
        o_hi[off] = hh; o_lo[off] = ll;
    }
}

extern "C" void kernel_launch(void* const* d_in, const int* in_sizes, int n_in,
                              void* d_out, int out_size, void* d_ws, size_t ws_size,
                              hipStream_t stream) {
    (void)in_sizes; (void)n_in; (void)out_size; (void)ws_size;
    const float* x_in   = (const float*)d_in[0];
    const int*   mask   = (const int*)d_in[1];
    const float* ln1_g  = (const float*)d_in[2];
    const float* ln1_b  = (const float*)d_in[3];
    const float* qkv_w  = (const float*)d_in[4];
    const float* proj_w = (const float*)d_in[5];
    const float* proj_b = (const float*)d_in[6];
    const float* ln2_g  = (const float*)d_in[7];
    const float* ln2_b  = (const float*)d_in[8];
    const float* ffn_w1 = (const float*)d_in[9];
    const float* ffn_b1 = (const float*)d_in[10];
    const float* ffn_w2 = (const float*)d_in[11];
    const float* ffn_b2 = (const float*)d_in[12];

    const size_t xsz = (size_t)BB * NN * DIM;          // 2,621,440 elems
    float* xbuf     = (float*)d_out;                   // residual stream
    float* attn_all = (float*)d_out + xsz;             // [depth,B,H,N,N]

    // -------- workspace carve --------
    unsigned short* Wq_hi = (unsigned short*)d_ws;                 // [1536][512]
    unsigned short* Wq_lo = Wq_hi + (size_t)1536 * 512;
    unsigned short* Wp_hi = Wq_lo + (size_t)1536 * 512;            // [512][512]
    unsigned short* Wp_lo = Wp_hi + (size_t)512 * 512;
    unsigned short* W1_hi = Wp_lo + (size_t)512 * 512;             // [4096][512]
    unsigned short* W1_lo = W1_hi + (size_t)4096 * 512;
    unsigned short* W2_hi = W1_lo + (size_t)4096 * 512;            // [512][4096]
    unsigned short* W2_lo = W2_hi + (size_t)4096 * 512;
    unsigned short* h_hi  = W2_lo + (size_t)4096 * 512;            // [5120][512]
    unsigned short* h_lo  = h_hi + xsz;
    unsigned short* U     = h_lo + xsz;
    unsigned short* qk_hi = U;                                     // [5120][1024]
    unsigned short* qk_lo = qk_hi + (size_t)5120 * 1024;
    float*          Vf    = (float*)(qk_lo + (size_t)5120 * 1024); // [5120][512] fp32
    unsigned short* vt_hi = (unsigned short*)(Vf + xsz);           // per b: [512][2560]
    unsigned short* vt_lo = vt_hi + (size_t)2 * 512 * 2560;
    unsigned short* o_hi  = vt_lo + (size_t)2 * 512 * 2560;        // [5120][512]
    unsigned short* o_lo  = o_hi + xsz;
    unsigned short* g_hi  = U;                                     // alias: [5120][4096]
    unsigned short* g_lo  = g_hi + (size_t)5120 * 4096;

    hipMemcpyAsync(xbuf, x_in, xsz * sizeof(float), hipMemcpyDeviceToDevice, stream);

    dim3 blk(256);
    const int M = BB * NN;  // 5120

    for (int j = 0; j < DEPTH; ++j) {
        // -------- weight prep --------
        tsplit_kernel<<<dim3(1536 / 32, 512 / 32, 1), blk, 0, stream>>>(
            qkv_w + (size_t)j * 512 * 1536, 1536, 0, Wq_hi, Wq_lo, 512, 0);
        tsplit_kernel<<<dim3(512 / 32, 512 / 32, 1), blk, 0, stream>>>(
            proj_w + (size_t)j * 512 * 512, 512, 0, Wp_hi, Wp_lo, 512, 0);
        tsplit_kernel<<<dim3(4096 / 32, 512 / 32, 1), blk, 0, stream>>>(
            ffn_w1 + (size_t)j * 512 * 4096, 4096, 0, W1_hi, W1_lo, 512, 0);
        tsplit_kernel<<<dim3(512 / 32, 4096 / 32, 1), blk, 0, stream>>>(
            ffn_w2 + (size_t)j * 4096 * 512, 512, 0, W2_hi, W2_lo, 4096, 0);

        // -------- LN1 -> h planes --------
        ln_split_kernel<<<dim3(M / 4), blk, 0, stream>>>(xbuf, ln1_g + j * DIM, ln1_b + j * DIM, h_hi, h_lo);

        // -------- QKV (Q,K part) --------
        gemm_mfma<128, false, false, true, true, 1><<<dim3(8, 40, 1), blk, 0, stream>>>(
            h_hi, h_lo, DIM, 0, 0,
            Wq_hi, Wq_lo, DIM, 0, 0,
            nullptr, qk_hi, qk_lo, 1024, 0, 0,
            DIM, 1.f, nullptr, 1);
        // -------- QKV (V part): fp32 out --------
        gemm_mfma<64, false, false, false, true, 1><<<dim3(8, 40, 1), blk, 0, stream>>>(
            h_hi, h_lo, DIM, 0, 0,
            Wq_hi + (size_t)1024 * 512, Wq_lo + (size_t)1024 * 512, DIM, 0, 0,
            Vf, nullptr, nullptr, DIM, 0, 0,
            DIM, 1.f, nullptr, 1);
        // -------- V transpose+split per batch --------
        tsplit_kernel<<<dim3(512 / 32, 2560 / 32, BB), blk, 0, stream>>>(
            Vf, DIM, (long long)NN * DIM, vt_hi, vt_lo, NN, (long long)DIM * NN);

        float* attn_j = attn_all + (size_t)j * BB * HEADS * NN * NN;
        // -------- QK^T * scale -> logits --------
        gemm_mfma<128, false, false, false, true, 1><<<dim3(20, 20, BB * HEADS), blk, 0, stream>>>(
            qk_hi, qk_lo, 1024, (long long)NN * 1024, HD,
            qk_hi + 512, qk_lo + 512, 1024, (long long)NN * 1024, HD,
            attn_j, nullptr, nullptr, NN, (long long)HEADS * NN * NN, (long long)NN * NN,
            HD, ATT_SCALE, nullptr, HEADS);

        // -------- fused masked softmax + PV --------
        softmax_pv_kernel<<<dim3(NN / QB, HEADS, BB), blk, 0, stream>>>(
            attn_j, mask, vt_hi, vt_lo, o_hi, o_lo);

        // -------- proj: x += o @ Wp + b (split-K=2, atomic) --------
        gemm_mfma<64, false, true, false, true, 2><<<dim3(8, 40, 2), blk, 0, stream>>>(
            o_hi, o_lo, DIM, 0, 0,
            Wp_hi, Wp_lo, DIM, 0, 0,
            xbuf, nullptr, nullptr, DIM, 0, 0,
            DIM, 1.f, proj_b + j * DIM, 1);

        // -------- LN2 -> h planes --------
        ln_split_kernel<<<dim3(M / 4), blk, 0, stream>>>(xbuf, ln2_g + j * DIM, ln2_b + j * DIM, h_hi, h_lo);

        // -------- FFN1: gelu(h @ W1 + b1) -> g planes --------
        gemm_mfma<128, true, false, true, true, 1><<<dim3(32, 40, 1), blk, 0, stream>>>(
            h_hi, h_lo, DIM, 0, 0,
            W1_hi, W1_lo, DIM, 0, 0,
            nullptr, g_hi, g_lo, 4096, 0, 0,
            DIM, 1.f, ffn_b1 + (size_t)j * 4096, 1);

        // -------- FFN2: x += g @ W2 + b2 (split-K=4, atomic) --------
        gemm_mfma<64, false, true, false, true, 4><<<dim3(8, 40, 4), blk, 0, stream>>>(
            g_hi, g_lo, 4096, 0, 0,
            W2_hi, W2_lo, 4096, 0, 0,
            xbuf, nullptr, nullptr, DIM, 0, 0,
            4096, 1.f, ffn_b2 + j * DIM, 1);
    }
}

// Round 5
// 3123.765 us; speedup vs baseline: 1.2143x; 1.2143x over previous
//
#include <hip/hip_runtime.h>
#include <math.h>

#define DEPTH 3
#define HEADS 8
#define DIM 512
#define NCLS 4
#define EPSV 1e-5f
#define BB 2
#define NN 2560
#define HD 64
#define ATT_SCALE 0.125f

typedef __attribute__((ext_vector_type(8))) short bf16x8;
typedef __attribute__((ext_vector_type(4))) float f32x4;

// ---------------- bf16 split helpers (hi + lo ~= fp32, RNE both) ----------------
__device__ inline unsigned short bf16_rne(float f) {
    unsigned int u = __float_as_uint(f);
    u += 0x7FFFu + ((u >> 16) & 1u);
    return (unsigned short)(u >> 16);
}
__device__ inline float bf16_tof(unsigned short h) {
    return __uint_as_float(((unsigned int)h) << 16);
}
__device__ inline void split2(float f, unsigned short& hi, unsigned short& lo) {
    hi = bf16_rne(f);
    lo = bf16_rne(f - bf16_tof(hi));
}

__device__ inline float gelu_tanh(float x) {
    float x3 = x * x * x;
    return 0.5f * x * (1.f + tanhf(0.7978845608028654f * (x + 0.044715f * x3)));
}

// LDS chunk swizzle: plane rows are 64B = 4 x 16B chunks. chunk' = chunk ^ ((row>>1)&3).
__device__ inline int swz(int row, int chunk) { return chunk ^ ((row >> 1) & 3); }

// async global->LDS, 16B per lane, wave-uniform LDS base + lane*16
__device__ inline void gll16(const void* g, void* l) {
    __builtin_amdgcn_global_load_lds(
        (const __attribute__((address_space(1))) void*)g,
        (__attribute__((address_space(3))) void*)l,
        16, 0, 0);
}

// Stage a bf16 plane tile [ROWS][32] into LDS (linear dest, source-swizzled).
template<int ROWS>
__device__ inline void stage_plane(const unsigned short* gp, int ldp,
                                   unsigned short* ls, int lane, int wave) {
#pragma unroll
    for (int q = 0; q < ROWS / 64; ++q) {
        int base = wave * (ROWS * 16) + q * 1024;   // wave-uniform byte base
        int lpos = base + lane * 16;
        int row  = lpos >> 6;
        int cl   = (lpos >> 4) & 3;
        int cg   = swz(row, cl);
        gll16(gp + (size_t)row * ldp + cg * 8, (char*)ls + base);
    }
}

// Reg-stage an fp32 A tile [128][32], converting to hi/lo bf16 planes in LDS
// (swizzled ds_write addresses).
__device__ inline void stage_a_f32(const float* ga, int lda,
                                   unsigned short* lhi, unsigned short* llo, int tid) {
    int row = tid >> 1, half = tid & 1;
    const float* src = ga + (size_t)row * lda + half * 16;
#pragma unroll
    for (int c2 = 0; c2 < 2; ++c2) {
        float4 p0 = *(const float4*)(src + c2 * 8);
        float4 p1 = *(const float4*)(src + c2 * 8 + 4);
        float v[8] = {p0.x, p0.y, p0.z, p0.w, p1.x, p1.y, p1.z, p1.w};
        bf16x8 hv, lv;
#pragma unroll
        for (int i = 0; i < 8; ++i) {
            unsigned short h, l;
            split2(v[i], h, l);
            hv[i] = (short)h; lv[i] = (short)l;
        }
        int chunk = half * 2 + c2;
        int idx = row * 32 + swz(row, chunk) * 8;
        *(bf16x8*)&lhi[idx] = hv;
        *(bf16x8*)&llo[idx] = lv;
    }
}

// ---------------- MFMA split-bf16 GEMM ----------------
// C[BMxBN tile] = alpha * A[M,K] @ B^T[N,K] (+bias)(gelu)(+=resid)
// A: fp32 (A_F32) or hi/lo bf16 planes, [M][K] k-contiguous.
// B: hi/lo bf16 planes, [N][K] k-contiguous.
// SPLITK==2 (hybrid, no atomics): kz=0 does xbuf[off] += r (incl. bias);
// kz=1 writes partial to Cp. Caller must launch addbuf_kernel afterwards.
template<int BN, bool A_F32, bool DO_GELU, bool DO_RESID, bool SPLIT_OUT, bool ZSWZ, int SPLITK>
__global__ __launch_bounds__(256, (BN == 128 ? 2 : 3)) void gemm_mfma(
    const float* __restrict__ Af,
    const unsigned short* __restrict__ A_hi, const unsigned short* __restrict__ A_lo,
    int lda, long long sAb, long long sAh,
    const unsigned short* __restrict__ B_hi, const unsigned short* __restrict__ B_lo,
    int ldb, long long sBb, long long sBh,
    float* __restrict__ Cf,
    unsigned short* __restrict__ C_hi, unsigned short* __restrict__ C_lo,
    float* __restrict__ Cp,
    int ldc, long long sCb, long long sCh,
    int K, float alpha, const float* __restrict__ bias, int nh)
{
    constexpr int BM = 128;
    constexpr int WAVES_N = (BN == 128) ? 2 : 1;
    constexpr int WM = (WAVES_N == 2) ? 64 : 32;
    constexpr int WN = 64;
    constexpr int MF = WM / 16;
    constexpr int NF = WN / 16;

    __shared__ unsigned short As_hi[BM * 32], As_lo[BM * 32];
    __shared__ unsigned short Bs_hi[BN * 32], Bs_lo[BN * 32];

    int bx = blockIdx.x, by = blockIdx.y, bzz = blockIdx.z;
    if constexpr (ZSWZ) {
        int gx = gridDim.x, gy = gridDim.y, gz = gridDim.z;
        int pb = gx * gy;
        int total = pb * gz;
        int flat = bx + gx * (by + gy * bzz);
        int cpx = total >> 3;
        int nf = (flat & 7) * cpx + (flat >> 3);
        bzz = nf / pb;
        int r = nf - bzz * pb;
        by = r / gx;
        bx = r - by * gx;
    }

    int kz = 0;
    if constexpr (SPLITK > 1) { kz = bzz; bzz = 0; }

    const int bz = bzz / nh, hz = bzz % nh;
    const long long aoff = (long long)bz * sAb + (long long)hz * sAh;
    const long long boff = (long long)bz * sBb + (long long)hz * sBh;
    const long long coff = (long long)bz * sCb + (long long)hz * sCh;
    if (A_F32) { Af += aoff; } else { A_hi += aoff; A_lo += aoff; }
    B_hi += boff; B_lo += boff;
    if constexpr (SPLITK == 1) {
        if (SPLIT_OUT) { C_hi += coff; C_lo += coff; } else { Cf += coff; }
    }

    const int tid  = threadIdx.x;
    const int lane = tid & 63;
    const int wave = tid >> 6;
    const int row0 = by * BM;
    const int n0   = bx * BN;
    const int wr = (WAVES_N == 2) ? (wave >> 1) : wave;
    const int wc = (WAVES_N == 2) ? (wave & 1) : 0;
    const int lr = lane & 15;
    const int cg = lane >> 4;

    f32x4 acc[MF][NF];
#pragma unroll
    for (int m = 0; m < MF; ++m)
#pragma unroll
        for (int n = 0; n < NF; ++n)
#pragma unroll
            for (int i = 0; i < 4; ++i) acc[m][n][i] = 0.f;

    const int kb = kz * (K / SPLITK);
    const int ke = kb + K / SPLITK;
    for (int k0 = kb; k0 < ke; k0 += 32) {
        if constexpr (A_F32) {
            stage_a_f32(Af + (size_t)row0 * lda + k0, lda, As_hi, As_lo, tid);
        } else {
            stage_plane<BM>(A_hi + (size_t)row0 * lda + k0, lda, As_hi, lane, wave);
            stage_plane<BM>(A_lo + (size_t)row0 * lda + k0, lda, As_lo, lane, wave);
        }
        stage_plane<BN>(B_hi + (size_t)n0 * ldb + k0, ldb, Bs_hi, lane, wave);
        stage_plane<BN>(B_lo + (size_t)n0 * ldb + k0, ldb, Bs_lo, lane, wave);
        __syncthreads();

        bf16x8 ah[MF], al[MF], bh[NF], bl[NF];
#pragma unroll
        for (int m = 0; m < MF; ++m) {
            int r = wr * WM + m * 16 + lr;
            int idx = r * 32 + swz(r, cg) * 8;
            ah[m] = *(const bf16x8*)&As_hi[idx];
            al[m] = *(const bf16x8*)&As_lo[idx];
        }
#pragma unroll
        for (int n = 0; n < NF; ++n) {
            int r = wc * WN + n * 16 + lr;
            int idx = r * 32 + swz(r, cg) * 8;
            bh[n] = *(const bf16x8*)&Bs_hi[idx];
            bl[n] = *(const bf16x8*)&Bs_lo[idx];
        }
#pragma unroll
        for (int m = 0; m < MF; ++m)
#pragma unroll
            for (int n = 0; n < NF; ++n) {
                acc[m][n] = __builtin_amdgcn_mfma_f32_16x16x32_bf16(ah[m], bh[n], acc[m][n], 0, 0, 0);
                acc[m][n] = __builtin_amdgcn_mfma_f32_16x16x32_bf16(ah[m], bl[n], acc[m][n], 0, 0, 0);
                acc[m][n] = __builtin_amdgcn_mfma_f32_16x16x32_bf16(al[m], bh[n], acc[m][n], 0, 0, 0);
            }
        __syncthreads();
    }

    // epilogue: D lane map col = lane&15, row = (lane>>4)*4 + i
    float bv[NF];
#pragma unroll
    for (int n = 0; n < NF; ++n) {
        int col = n0 + wc * WN + n * 16 + lr;
        bv[n] = (bias && kz == 0) ? bias[col] : 0.f;
    }
#pragma unroll
    for (int m = 0; m < MF; ++m) {
#pragma unroll
        for (int n = 0; n < NF; ++n) {
            int col = n0 + wc * WN + n * 16 + lr;
#pragma unroll
            for (int i = 0; i < 4; ++i) {
                int row = row0 + wr * WM + m * 16 + cg * 4 + i;
                size_t off = (size_t)row * ldc + col;
                float r = alpha * acc[m][n][i] + bv[n];
                if constexpr (DO_GELU) r = gelu_tanh(r);
                if constexpr (SPLITK > 1) {
                    // hybrid: kz=0 residual-RMW into Cf (each elem owned by 1 block),
                    // kz=1 writes partial slice to Cp. No atomics.
                    if (kz == 0) Cf[off] += r;
                    else         Cp[off] = r;
                } else if constexpr (SPLIT_OUT) {
                    unsigned short h, l;
                    split2(r, h, l);
                    C_hi[off] = h; C_lo[off] = l;
                } else {
                    if constexpr (DO_RESID) r += Cf[off];
                    Cf[off] = r;
                }
            }
        }
    }
}

// ---------------- xbuf += P (split-K slice-1 fold-in) ----------------
// grid: 2560 blocks x 256 thr, one float4 per thread (5120*512 elems).
__global__ __launch_bounds__(256) void addbuf_kernel(const float* __restrict__ P,
                                                     float* __restrict__ xbuf) {
    int e4 = blockIdx.x * 256 + threadIdx.x;
    float4 a = ((const float4*)P)[e4];
    float4 x = ((const float4*)xbuf)[e4];
    x.x += a.x; x.y += a.y; x.z += a.z; x.w += a.w;
    ((float4*)xbuf)[e4] = x;
}

// ---------------- LayerNorm -> hi/lo bf16 planes ----------------
__global__ __launch_bounds__(256) void ln_split_kernel(const float* __restrict__ x,
                                                       const float* __restrict__ g,
                                                       const float* __restrict__ b,
                                                       unsigned short* __restrict__ ohi,
                                                       unsigned short* __restrict__ olo) {
    int wave = threadIdx.x >> 6;
    int lane = threadIdx.x & 63;
    int row  = blockIdx.x * 4 + wave;
    const float* xr = x + (size_t)row * DIM;
    float v[8];
    float s = 0.f, ss = 0.f;
#pragma unroll
    for (int i = 0; i < 8; ++i) {
        v[i] = xr[lane + i * 64];
        s += v[i]; ss += v[i] * v[i];
    }
#pragma unroll
    for (int off = 32; off >= 1; off >>= 1) {
        s  += __shfl_xor(s,  off, 64);
        ss += __shfl_xor(ss, off, 64);
    }
    float mu   = s * (1.f / DIM);
    float var  = ss * (1.f / DIM) - mu * mu;
    float rstd = rsqrtf(var + EPSV);
    size_t base = (size_t)row * DIM;
#pragma unroll
    for (int i = 0; i < 8; ++i) {
        int c = lane + i * 64;
        float r = (v[i] - mu) * rstd * g[c] + b[c];
        unsigned short h, l;
        split2(r, h, l);
        ohi[base + c] = h; olo[base + c] = l;
    }
}

// ---------------- transpose + split: fp32 [R][C] -> hi/lo bf16 [C][R] ----------------
__global__ __launch_bounds__(256) void tsplit_kernel(
    const float* __restrict__ in, int ldin, long long inBS,
    unsigned short* __restrict__ ohi, unsigned short* __restrict__ olo,
    int ldout, long long outBS) {
    __shared__ float tile[32][33];
    const float* src = in + (size_t)blockIdx.z * inBS;
    int r0 = blockIdx.y * 32, c0 = blockIdx.x * 32;
    int t = threadIdx.x;
    int r = t >> 3, cq = (t & 7) * 4;
    float4 v = *(const float4*)&src[(size_t)(r0 + r) * ldin + c0 + cq];
    tile[r][cq] = v.x; tile[r][cq + 1] = v.y; tile[r][cq + 2] = v.z; tile[r][cq + 3] = v.w;
    __syncthreads();
    unsigned short h[4], l[4];
#pragma unroll
    for (int i = 0; i < 4; ++i) split2(tile[cq + i][r], h[i], l[i]);
    size_t off = (size_t)blockIdx.z * outBS + (size_t)(c0 + r) * ldout + r0 + cq;
    *(ushort4*)&ohi[off] = make_ushort4(h[0], h[1], h[2], h[3]);
    *(ushort4*)&olo[off] = make_ushort4(l[0], l[1], l[2], l[3]);
}

// ---------------- Masked row softmax (in place, fp32) ----------------
__global__ __launch_bounds__(256) void softmax_kernel(float* __restrict__ attn,
                                                      const int* __restrict__ mask) {
    int q = blockIdx.x, h = blockIdx.y, b = blockIdx.z;
    float* row = attn + (((size_t)(b * HEADS + h)) * NN + q) * NN;
    int t = threadIdx.x;

    float v[10];
    bool ok[10];
    float lmax = -INFINITY;
#pragma unroll
    for (int i = 0; i < 10; ++i) {
        int col = t + i * 256;
        int cls = col >> 9;
        ok[i] = (cls >= NCLS) || (mask[b * NCLS + cls] != 0);
        v[i] = row[col];
        if (ok[i]) lmax = fmaxf(lmax, v[i]);
    }
    __shared__ float red[4];
#pragma unroll
    for (int off = 32; off >= 1; off >>= 1) lmax = fmaxf(lmax, __shfl_xor(lmax, off, 64));
    if ((t & 63) == 0) red[t >> 6] = lmax;
    __syncthreads();
    float m = fmaxf(fmaxf(red[0], red[1]), fmaxf(red[2], red[3]));
    __syncthreads();

    float lsum = 0.f;
#pragma unroll
    for (int i = 0; i < 10; ++i) {
        if (ok[i]) { v[i] = __expf(v[i] - m); lsum += v[i]; }
    }
#pragma unroll
    for (int off = 32; off >= 1; off >>= 1) lsum += __shfl_xor(lsum, off, 64);
    if ((t & 63) == 0) red[t >> 6] = lsum;
    __syncthreads();
    float inv = 1.f / (red[0] + red[1] + red[2] + red[3]);

#pragma unroll
    for (int i = 0; i < 10; ++i) {
        int col = t + i * 256;
        row[col] = ok[i] ? v[i] * inv : 0.f;
    }
}

extern "C" void kernel_launch(void* const* d_in, const int* in_sizes, int n_in,
                              void* d_out, int out_size, void* d_ws, size_t ws_size,
                              hipStream_t stream) {
    (void)in_sizes; (void)n_in; (void)out_size; (void)ws_size;
    const float* x_in   = (const float*)d_in[0];
    const int*   mask   = (const int*)d_in[1];
    const float* ln1_g  = (const float*)d_in[2];
    const float* ln1_b  = (const float*)d_in[3];
    const float* qkv_w  = (const float*)d_in[4];
    const float* proj_w = (const float*)d_in[5];
    const float* proj_b = (const float*)d_in[6];
    const float* ln2_g  = (const float*)d_in[7];
    const float* ln2_b  = (const float*)d_in[8];
    const float* ffn_w1 = (const float*)d_in[9];
    const float* ffn_b1 = (const float*)d_in[10];
    const float* ffn_w2 = (const float*)d_in[11];
    const float* ffn_b2 = (const float*)d_in[12];

    const size_t xsz = (size_t)BB * NN * DIM;          // 2,621,440 elems
    float* xbuf     = (float*)d_out;                   // residual stream
    float* attn_all = (float*)d_out + xsz;             // [depth,B,H,N,N]

    // -------- workspace carve --------
    unsigned short* Wq_hi = (unsigned short*)d_ws;                 // [1536][512]
    unsigned short* Wq_lo = Wq_hi + (size_t)1536 * 512;
    unsigned short* Wp_hi = Wq_lo + (size_t)1536 * 512;            // [512][512]
    unsigned short* Wp_lo = Wp_hi + (size_t)512 * 512;
    unsigned short* W1_hi = Wp_lo + (size_t)512 * 512;             // [4096][512]
    unsigned short* W1_lo = W1_hi + (size_t)4096 * 512;
    unsigned short* W2_hi = W1_lo + (size_t)4096 * 512;            // [512][4096]
    unsigned short* W2_lo = W2_hi + (size_t)4096 * 512;
    unsigned short* h_hi  = W2_lo + (size_t)4096 * 512;            // [5120][512]
    unsigned short* h_lo  = h_hi + xsz;
    unsigned short* U     = h_lo + xsz;
    unsigned short* qk_hi = U;                                     // [5120][1024]
    unsigned short* qk_lo = qk_hi + (size_t)5120 * 1024;
    float*          Vf    = (float*)(qk_lo + (size_t)5120 * 1024); // [5120][512] fp32
    unsigned short* vt_hi = (unsigned short*)(Vf + xsz);           // per b: [512][2560]
    unsigned short* vt_lo = vt_hi + (size_t)2 * 512 * 2560;
    unsigned short* o_hi  = vt_lo + (size_t)2 * 512 * 2560;        // [5120][512]
    unsigned short* o_lo  = o_hi + xsz;
    unsigned short* g_hi  = U;                                     // alias: [5120][4096]
    unsigned short* g_lo  = g_hi + (size_t)5120 * 4096;
    // Split-K slice-1 partial buffer: h region = 2*xsz ushorts = EXACTLY xsz floats.
    // Live only while h planes are dead (during proj and during FFN2).
    float* Pk = (float*)h_hi;

    hipMemcpyAsync(xbuf, x_in, xsz * sizeof(float), hipMemcpyDeviceToDevice, stream);

    dim3 blk(256);
    const int M = BB * NN;  // 5120

    for (int j = 0; j < DEPTH; ++j) {
        // -------- weight prep --------
        tsplit_kernel<<<dim3(1536 / 32, 512 / 32, 1), blk, 0, stream>>>(
            qkv_w + (size_t)j * 512 * 1536, 1536, 0, Wq_hi, Wq_lo, 512, 0);
        tsplit_kernel<<<dim3(512 / 32, 512 / 32, 1), blk, 0, stream>>>(
            proj_w + (size_t)j * 512 * 512, 512, 0, Wp_hi, Wp_lo, 512, 0);
        tsplit_kernel<<<dim3(4096 / 32, 512 / 32, 1), blk, 0, stream>>>(
            ffn_w1 + (size_t)j * 512 * 4096, 4096, 0, W1_hi, W1_lo, 512, 0);
        tsplit_kernel<<<dim3(512 / 32, 4096 / 32, 1), blk, 0, stream>>>(
            ffn_w2 + (size_t)j * 4096 * 512, 512, 0, W2_hi, W2_lo, 4096, 0);

        // -------- LN1 -> h planes --------
        ln_split_kernel<<<dim3(M / 4), blk, 0, stream>>>(xbuf, ln1_g + j * DIM, ln1_b + j * DIM, h_hi, h_lo);

        // -------- QKV (Q,K part): planes out [5120][1024] --------
        gemm_mfma<128, false, false, false, true, true, 1><<<dim3(8, 40, 1), blk, 0, stream>>>(
            nullptr, h_hi, h_lo, DIM, 0, 0,
            Wq_hi, Wq_lo, DIM, 0, 0,
            nullptr, qk_hi, qk_lo, nullptr, 1024, 0, 0,
            DIM, 1.f, nullptr, 1);
        // -------- QKV (V part): fp32 out [5120][512] --------
        gemm_mfma<64, false, false, false, false, true, 1><<<dim3(8, 40, 1), blk, 0, stream>>>(
            nullptr, h_hi, h_lo, DIM, 0, 0,
            Wq_hi + (size_t)1024 * 512, Wq_lo + (size_t)1024 * 512, DIM, 0, 0,
            Vf, nullptr, nullptr, nullptr, DIM, 0, 0,
            DIM, 1.f, nullptr, 1);
        // -------- V transpose+split per batch: [2560][512] -> [512][2560] --------
        tsplit_kernel<<<dim3(512 / 32, 2560 / 32, BB), blk, 0, stream>>>(
            Vf, DIM, (long long)NN * DIM, vt_hi, vt_lo, NN, (long long)DIM * NN);

        float* attn_j = attn_all + (size_t)j * BB * HEADS * NN * NN;
        // -------- QK^T * scale -> logits (fp32, per b,h) --------
        gemm_mfma<128, false, false, false, false, true, 1><<<dim3(20, 20, BB * HEADS), blk, 0, stream>>>(
            nullptr, qk_hi, qk_lo, 1024, (long long)NN * 1024, HD,
            qk_hi + 512, qk_lo + 512, 1024, (long long)NN * 1024, HD,
            attn_j, nullptr, nullptr, nullptr, NN, (long long)HEADS * NN * NN, (long long)NN * NN,
            HD, ATT_SCALE, nullptr, HEADS);

        // -------- masked softmax in place --------
        softmax_kernel<<<dim3(NN, HEADS, BB), blk, 0, stream>>>(attn_j, mask);

        // -------- PV: probs(fp32) @ V -> o planes --------
        gemm_mfma<64, true, false, false, true, true, 1><<<dim3(1, 20, BB * HEADS), blk, 0, stream>>>(
            attn_j, nullptr, nullptr, NN, (long long)HEADS * NN * NN, (long long)NN * NN,
            vt_hi, vt_lo, NN, (long long)DIM * NN, (long long)HD * NN,
            nullptr, o_hi, o_lo, nullptr, DIM, (long long)NN * DIM, HD,
            NN, 1.f, nullptr, HEADS);

        // -------- proj: x += o @ Wp + b  (hybrid split-K=2, h region dead) --------
        gemm_mfma<64, false, false, false, false, true, 2><<<dim3(8, 40, 2), blk, 0, stream>>>(
            nullptr, o_hi, o_lo, DIM, 0, 0,
            Wp_hi, Wp_lo, DIM, 0, 0,
            xbuf, nullptr, nullptr, Pk, DIM, 0, 0,
            DIM, 1.f, proj_b + j * DIM, 1);
        addbuf_kernel<<<dim3(2560), blk, 0, stream>>>(Pk, xbuf);

        // -------- LN2 -> h planes (after reduce; overwrites Pk region) --------
        ln_split_kernel<<<dim3(M / 4), blk, 0, stream>>>(xbuf, ln2_g + j * DIM, ln2_b + j * DIM, h_hi, h_lo);

        // -------- FFN1: gelu(h @ W1 + b1) -> g planes --------
        gemm_mfma<128, false, true, false, true, true, 1><<<dim3(32, 40, 1), blk, 0, stream>>>(
            nullptr, h_hi, h_lo, DIM, 0, 0,
            W1_hi, W1_lo, DIM, 0, 0,
            nullptr, g_hi, g_lo, nullptr, 4096, 0, 0,
            DIM, 1.f, ffn_b1 + (size_t)j * 4096, 1);

        // -------- FFN2: x += g @ W2 + b2  (hybrid split-K=2, h dead again) --------
        gemm_mfma<64, false, false, false, false, true, 2><<<dim3(8, 40, 2), blk, 0, stream>>>(
            nullptr, g_hi, g_lo, 4096, 0, 0,
            W2_hi, W2_lo, 4096, 0, 0,
            xbuf, nullptr, nullptr, Pk, DIM, 0, 0,
            4096, 1.f, ffn_b2 + j * DIM, 1);
        addbuf_kernel<<<dim3(2560), blk, 0, stream>>>(Pk, xbuf);
    }
}